// Round 3
// baseline (898.875 us; speedup 1.0000x reference)
//
#include <hip/hip_runtime.h>

typedef unsigned short u16;
typedef unsigned int   u32;

typedef __attribute__((ext_vector_type(8))) short bf16x8;
typedef __attribute__((ext_vector_type(4))) float f32x4;

__device__ __forceinline__ u16 f2bf(float f) {
  u32 u = __float_as_uint(f);
  u32 r = (u + 0x7fffu + ((u >> 16) & 1u)) >> 16;
  return (u16)r;
}

__device__ __forceinline__ void async16(const void* g, void* l) {
  __builtin_amdgcn_global_load_lds(
      (const __attribute__((address_space(1))) u32*)g,
      (__attribute__((address_space(3))) u32*)l, 16, 0, 0);
}

// ---------------------------------------------------------------------------
// conv1 (1x1, 512->64) + BN + leaky + reorg, writes in_bf channels [0,256)
// one thread per (b,h,w) of 38x38; 32 oc per thread (blockIdx.y = oc half)
// grid 362 blocks -> 1.41 blocks/CU (was 181 = 0.71, 75 CUs idle)
// ---------------------------------------------------------------------------
__global__ __launch_bounds__(256) void conv1_reorg_kern(
    const float* __restrict__ stage5, const float* __restrict__ w1,
    const float* __restrict__ g1, const float* __restrict__ b1,
    const float* __restrict__ m1, const float* __restrict__ v1,
    u16* __restrict__ in_bf)
{
  __shared__ float wlds[64][40];   // [ic_local][oc_local]; 40*4=160B rows keep float4 aligned
  __shared__ float2 bn[32];
  const int t = threadIdx.x;
  const int ocb = blockIdx.y * 32;
  int m = blockIdx.x * 256 + t;
  bool valid = (m < 46208);
  int mm = valid ? m : 46207;
  int b = mm / 1444;
  int hw = mm - b * 1444;
  const float* src = stage5 + (size_t)b * (512 * 1444) + hw;
  if (t < 32) {
    float sc = g1[ocb + t] * rsqrtf(v1[ocb + t] + 1e-5f);
    bn[t].x = sc;
    bn[t].y = b1[ocb + t] - m1[ocb + t] * sc;
  }
  float acc[32];
#pragma unroll
  for (int i = 0; i < 32; ++i) acc[i] = 0.f;

  for (int ic0 = 0; ic0 < 512; ic0 += 64) {
    __syncthreads();
#pragma unroll
    for (int r = 0; r < 8; ++r) {
      int idx = r * 256 + t;          // = oc_l*64 + icl : coalesced w1 rows
      int oc_l = idx >> 6, icl = idx & 63;
      wlds[icl][oc_l] = w1[(size_t)(ocb + oc_l) * 512 + ic0 + icl];
    }
    __syncthreads();
    for (int g = 0; g < 4; ++g) {
      float av[16];
#pragma unroll
      for (int u = 0; u < 16; ++u)
        av[u] = src[(size_t)(ic0 + g * 16 + u) * 1444];
#pragma unroll
      for (int u = 0; u < 16; ++u) {
#pragma unroll
        for (int o4 = 0; o4 < 8; ++o4) {
          float4 wv = *(const float4*)&wlds[g * 16 + u][o4 * 4];
          acc[o4 * 4 + 0] += av[u] * wv.x;
          acc[o4 * 4 + 1] += av[u] * wv.y;
          acc[o4 * 4 + 2] += av[u] * wv.z;
          acc[o4 * 4 + 3] += av[u] * wv.w;
        }
      }
    }
  }
  if (valid) {
    int h = hw / 38, wq = hw - h * 38;
    int ho = h >> 1, wo = wq >> 1, q = ((h & 1) << 1) | (wq & 1);
    u16* dst = in_bf + (((size_t)b * 21 + 1 + ho) * 21 + 1 + wo) * 1280 + q * 64 + ocb;
#pragma unroll
    for (int gg = 0; gg < 8; ++gg) {
      int oc = gg * 4;
      float v0 = acc[oc + 0] * bn[oc + 0].x + bn[oc + 0].y;
      float v1 = acc[oc + 1] * bn[oc + 1].x + bn[oc + 1].y;
      float v2 = acc[oc + 2] * bn[oc + 2].x + bn[oc + 2].y;
      float v3 = acc[oc + 3] * bn[oc + 3].x + bn[oc + 3].y;
      v0 = v0 > 0.f ? v0 : 0.1f * v0;
      v1 = v1 > 0.f ? v1 : 0.1f * v1;
      v2 = v2 > 0.f ? v2 : 0.1f * v2;
      v3 = v3 > 0.f ? v3 : 0.1f * v3;
      u32 lo = (u32)f2bf(v0) | ((u32)f2bf(v1) << 16);
      u32 hi = (u32)f2bf(v2) | ((u32)f2bf(v3) << 16);
      u32* dp = (u32*)(dst + oc);
      dp[0] = lo; dp[1] = hi;
    }
  }
}

// ---------------------------------------------------------------------------
// stage6 NCHW -> in_bf NHWC channels [256,1280), bf16, LDS-tiled transpose
// ---------------------------------------------------------------------------
__global__ __launch_bounds__(256) void fill_stage6_kern(
    const float* __restrict__ s6, u16* __restrict__ in_bf)
{
  __shared__ u16 tile[64][66];
  const int t = threadIdx.x;
  const int jt = blockIdx.x, ct = blockIdx.y, b = blockIdx.z;
  const int ij0 = jt * 64, c0 = ct * 64;
  const int col = t & 63, rr = t >> 6;
#pragma unroll
  for (int r = 0; r < 16; ++r) {
    int cl = r * 4 + rr;
    int ij = ij0 + col;
    float v = 0.f;
    if (ij < 361) v = s6[((size_t)b * 1024 + c0 + cl) * 361 + ij];
    tile[cl][col] = f2bf(v);
  }
  __syncthreads();
#pragma unroll
  for (int r = 0; r < 16; ++r) {
    int ijl = r * 4 + rr;
    int ij = ij0 + ijl;
    if (ij < 361) {
      int i = ij / 19, j = ij - i * 19;
      in_bf[(((size_t)b * 21 + 1 + i) * 21 + 1 + j) * 1280 + 256 + c0 + col] =
          tile[col][ijl];   // channel=col, ij=ijl
    }
  }
}

// ---------------------------------------------------------------------------
// w2 (1024,1280,3,3) fp32 -> w2bf[oc][khw*1280+ic] bf16, BN scale folded.
// Coalesced: block = (icb, oc); reads 1152 contiguous floats (128 ic x 9 khw),
// transposes through LDS, writes 9 segments of 128 u16.
// (old version read at stride 36B -> ~9x HBM fetch amplification)
// ---------------------------------------------------------------------------
__global__ __launch_bounds__(256) void prep_w2_kern(
    const float* __restrict__ w2, const float* __restrict__ g2,
    const float* __restrict__ v2, u16* __restrict__ w2bf)
{
  __shared__ u16 tile[9 * 130];    // [khw][ic_l], pad 130 breaks 9-way write conflicts
  const int t = threadIdx.x;
  const int icb = blockIdx.x;      // 0..9
  const int oc = blockIdx.y;       // 0..1023
  const int ic0 = icb * 128;
  const float sc = g2[oc] * rsqrtf(v2[oc] + 1e-5f);
  const float* src = w2 + (size_t)oc * 11520 + (size_t)ic0 * 9;
#pragma unroll
  for (int p = t; p < 1152; p += 256) {
    float v = src[p];
    int ic_l = p / 9;
    int khw = p - ic_l * 9;
    tile[khw * 130 + ic_l] = f2bf(v * sc);
  }
  __syncthreads();
  const int lane = t & 63;
  for (int s = t >> 6; s < 9; s += 4) {
    u32 v = (u32)tile[s * 130 + lane * 2] |
            ((u32)tile[s * 130 + lane * 2 + 1] << 16);
    ((u32*)(w2bf + (size_t)oc * 11520 + (size_t)s * 1280 + ic0))[lane] = v;
  }
}

// ---------------------------------------------------------------------------
// meta_state -> cls_w bf16 [600][1024], cls_b fp32 [600]; shift2 fp32 [1024]
// ---------------------------------------------------------------------------
__global__ __launch_bounds__(256) void prep_small_kern(
    const float* __restrict__ meta, const float* __restrict__ g2,
    const float* __restrict__ b2, const float* __restrict__ m2,
    const float* __restrict__ v2, u16* __restrict__ clsw,
    float* __restrict__ clsb, float* __restrict__ shift2)
{
  int idx = blockIdx.x * 256 + threadIdx.x;   // exactly 614400 threads
  int cm = idx >> 10, k = idx & 1023;
  clsw[idx] = f2bf(meta[(size_t)cm * 1025 + k]);
  if (idx < 600) clsb[idx] = meta[(size_t)idx * 1025 + 1024];
  if (idx < 1024) {
    float sc = g2[idx] * rsqrtf(v2[idx] + 1e-5f);
    shift2[idx] = b2[idx] - m2[idx] * sc;
  }
}

// ---------------------------------------------------------------------------
// conv2: implicit GEMM, A=weights[1024][11520], B=input rows (halo via padded
// NHWC buffer). 128(oc) x 128(m) x 32 tiles, 4 waves, 16x16x32 bf16 MFMA.
//
// LDS layout (conflict-free): staging lane l of wave w holds
// (row = 16w + (l&15), kq = l>>4); global_load_lds puts it at base + l*16B,
// so fragment reads become  addr = rbase*64 + lane*16  -- linear in lane,
// zero bank conflicts (old layout: 64B row stride -> 3.35e7 conflict cycles).
//
// XCD swizzle: oc_tile = lin&7 so each XCD keeps one 2.95MB W slice L2-resident.
// ---------------------------------------------------------------------------
__global__ __launch_bounds__(256) void conv2_gemm_kern(
    const u16* __restrict__ Wg, const u16* __restrict__ Ig,
    const float* __restrict__ shift2, u16* __restrict__ pre)
{
  __shared__ u16 Wa[128 * 32];
  __shared__ u16 Ib[128 * 32];
  __shared__ float shft[128];
  const int t = threadIdx.x;
  const int w = t >> 6, lane = t & 63;
  const int lin = blockIdx.x + 91 * blockIdx.y;
  const int m0 = (lin >> 3) * 128;
  const int oc0 = (lin & 7) * 128;

  if (t < 128) shft[t] = shift2[oc0 + t];

  const int rw = ((t >> 6) << 4) | (t & 15);  // row = wave*16 + (lane&15)
  const int rpart = ((t >> 4) & 3) * 8;       // kq*8 elements
  const u16* pW0 = Wg + (size_t)(oc0 + rw) * 11520 + rpart;
  const u16* pW1 = pW0 + (size_t)64 * 11520;

  int mA = m0 + rw;       if (mA > 11551) mA = 11551;
  int mB = m0 + 64 + rw;  if (mB > 11551) mB = 11551;
  int bA = mA / 361, ijA = mA - bA * 361;
  int ohA = ijA / 19, owA = ijA - ohA * 19;
  int bB = mB / 361, ijB = mB - bB * 361;
  int ohB = ijB / 19, owB = ijB - ohB * 19;
  const u16* pI0 = Ig + (size_t)((bA * 21 + ohA) * 21 + owA) * 1280 + rpart;
  const u16* pI1 = Ig + (size_t)((bB * 21 + ohB) * 21 + owB) * 1280 + rpart;

  u16* waS0 = &Wa[(w * 64) * 8];
  u16* waS1 = &Wa[(256 + w * 64) * 8];
  u16* ibS0 = &Ib[(w * 64) * 8];
  u16* ibS1 = &Ib[(256 + w * 64) * 8];

  const int aBase = (w >> 1) * 2048 + lane * 8;
  const int bBase = (w & 1) * 2048 + lane * 8;

  f32x4 acc[4][4] = {};

  for (int khw = 0; khw < 9; ++khw) {
    const int kh = khw / 3, kw = khw - kh * 3;
    const size_t iOffB = (size_t)(kh * 21 + kw) * 1280;
    const size_t wOffB = (size_t)khw * 1280;
    for (int icc = 0; icc < 40; ++icc) {
      const size_t io = iOffB + (size_t)icc * 32;
      const size_t wo_ = wOffB + (size_t)icc * 32;
      async16(pW0 + wo_, waS0);
      async16(pW1 + wo_, waS1);
      async16(pI0 + io, ibS0);
      async16(pI1 + io, ibS1);
      __syncthreads();
      bf16x8 af[4], bfv[4];
#pragma unroll
      for (int i = 0; i < 4; ++i)
        af[i] = *(const bf16x8*)&Wa[aBase + i * 512];
#pragma unroll
      for (int j = 0; j < 4; ++j)
        bfv[j] = *(const bf16x8*)&Ib[bBase + j * 512];
#pragma unroll
      for (int i = 0; i < 4; ++i)
#pragma unroll
        for (int j = 0; j < 4; ++j)
          acc[i][j] = __builtin_amdgcn_mfma_f32_16x16x32_bf16(
              af[i], bfv[j], acc[i][j], 0, 0, 0);
      __syncthreads();
    }
  }

  const int aRow = (w >> 1) * 64, bRow = (w & 1) * 64;
  const int lq = lane >> 4, lr = lane & 15;
#pragma unroll
  for (int j = 0; j < 4; ++j) {
    int m = m0 + bRow + j * 16 + lr;
    if (m >= 11552) continue;
    u16* prow = pre + (size_t)m * 1024 + oc0;
#pragma unroll
    for (int i = 0; i < 4; ++i) {
      int ocl = aRow + i * 16 + lq * 4;
      float v0 = acc[i][j][0] + shft[ocl + 0]; v0 = v0 > 0.f ? v0 : 0.1f * v0;
      float v1 = acc[i][j][1] + shft[ocl + 1]; v1 = v1 > 0.f ? v1 : 0.1f * v1;
      float v2 = acc[i][j][2] + shft[ocl + 2]; v2 = v2 > 0.f ? v2 : 0.1f * v2;
      float v3 = acc[i][j][3] + shft[ocl + 3]; v3 = v3 > 0.f ? v3 : 0.1f * v3;
      u32 lo = (u32)f2bf(v0) | ((u32)f2bf(v1) << 16);
      u32 hi = (u32)f2bf(v2) | ((u32)f2bf(v3) << 16);
      u32* dp = (u32*)(prow + ocl);
      dp[0] = lo; dp[1] = hi;
    }
  }
}

// ---------------------------------------------------------------------------
// einsum: GEMM A=cls_w[600][1024], B=pre[11552][1024]; out fp32 + bias,
// scatter to (b, cm, ij) layout. Same conflict-free LDS scheme as conv2.
// ---------------------------------------------------------------------------
__global__ __launch_bounds__(256) void einsum_gemm_kern(
    const u16* __restrict__ Ag, const u16* __restrict__ Bg,
    const float* __restrict__ biasg, float* __restrict__ out)
{
  __shared__ u16 Wa[128 * 32];
  __shared__ u16 Ib[128 * 32];
  __shared__ float sbias[128];
  const int t = threadIdx.x;
  const int w = t >> 6, lane = t & 63;
  const int m0 = blockIdx.x * 128;
  const int cm0 = blockIdx.y * 128;
  if (t < 128) { int c = cm0 + t; sbias[t] = (c < 600) ? biasg[c] : 0.f; }

  const int rw = ((t >> 6) << 4) | (t & 15);
  const int rpart = ((t >> 4) & 3) * 8;
  int rA0 = cm0 + rw;       if (rA0 > 599) rA0 = 599;
  int rA1 = cm0 + 64 + rw;  if (rA1 > 599) rA1 = 599;
  int rB0 = m0 + rw;        if (rB0 > 11551) rB0 = 11551;
  int rB1 = m0 + 64 + rw;   if (rB1 > 11551) rB1 = 11551;
  const u16* pA0 = Ag + (size_t)rA0 * 1024 + rpart;
  const u16* pA1 = Ag + (size_t)rA1 * 1024 + rpart;
  const u16* pB0 = Bg + (size_t)rB0 * 1024 + rpart;
  const u16* pB1 = Bg + (size_t)rB1 * 1024 + rpart;

  u16* waS0 = &Wa[(w * 64) * 8];
  u16* waS1 = &Wa[(256 + w * 64) * 8];
  u16* ibS0 = &Ib[(w * 64) * 8];
  u16* ibS1 = &Ib[(256 + w * 64) * 8];

  const int aBase = (w >> 1) * 2048 + lane * 8;
  const int bBase = (w & 1) * 2048 + lane * 8;

  f32x4 acc[4][4] = {};

  for (int kt = 0; kt < 32; ++kt) {
    const size_t off = (size_t)kt * 32;
    async16(pA0 + off, waS0);
    async16(pA1 + off, waS1);
    async16(pB0 + off, ibS0);
    async16(pB1 + off, ibS1);
    __syncthreads();
    bf16x8 af[4], bfv[4];
#pragma unroll
    for (int i = 0; i < 4; ++i)
      af[i] = *(const bf16x8*)&Wa[aBase + i * 512];
#pragma unroll
    for (int j = 0; j < 4; ++j)
      bfv[j] = *(const bf16x8*)&Ib[bBase + j * 512];
#pragma unroll
    for (int i = 0; i < 4; ++i)
#pragma unroll
      for (int j = 0; j < 4; ++j)
        acc[i][j] = __builtin_amdgcn_mfma_f32_16x16x32_bf16(
            af[i], bfv[j], acc[i][j], 0, 0, 0);
    __syncthreads();
  }

  const int aRow = (w >> 1) * 64, bRow = (w & 1) * 64;
  const int lq = lane >> 4, lr = lane & 15;
#pragma unroll
  for (int j = 0; j < 4; ++j) {
    int m = m0 + bRow + j * 16 + lr;
    if (m >= 11552) continue;
    int b = m / 361, ij = m - b * 361;
    float* obase = out + (size_t)b * 216600 + ij;
#pragma unroll
    for (int i = 0; i < 4; ++i) {
      int cml = aRow + i * 16 + lq * 4;
#pragma unroll
      for (int r = 0; r < 4; ++r) {
        int cm = cm0 + cml + r;
        if (cm < 600) obase[(size_t)cm * 361] = acc[i][j][r] + sbias[cml + r];
      }
    }
  }
}

// ---------------------------------------------------------------------------
// launch
// ---------------------------------------------------------------------------
extern "C" void kernel_launch(void* const* d_in, const int* in_sizes, int n_in,
                              void* d_out, int out_size, void* d_ws, size_t ws_size,
                              hipStream_t stream)
{
  const float* stage6 = (const float*)d_in[0];
  const float* stage5 = (const float*)d_in[1];
  const float* w1 = (const float*)d_in[2];
  const float* g1 = (const float*)d_in[3];
  const float* b1 = (const float*)d_in[4];
  const float* m1 = (const float*)d_in[5];
  const float* v1 = (const float*)d_in[6];
  const float* w2 = (const float*)d_in[7];
  const float* g2 = (const float*)d_in[8];
  const float* b2 = (const float*)d_in[9];
  const float* m2 = (const float*)d_in[10];
  const float* v2 = (const float*)d_in[11];
  const float* meta = (const float*)d_in[12];
  float* out = (float*)d_out;

  char* ws = (char*)d_ws;
  u16*   in_bf  = (u16*)(ws);                  // 36,126,720 B  (32*21*21*1280 bf16)
  u16*   w2bf   = (u16*)(ws + 36126720);       // 23,592,960 B  (1024*11520 bf16)
  u16*   prebf  = (u16*)(ws + 59719680);       // 23,658,496 B  (11552*1024 bf16)
  u16*   clsw   = (u16*)(ws + 83378176);       //  1,228,800 B  (600*1024 bf16)
  float* clsb   = (float*)(ws + 84606976);     //      2,560 B
  float* shift2 = (float*)(ws + 84609536);     //      4,096 B   total ~84.6 MB

  hipMemsetAsync(in_bf, 0, 36126720, stream);  // zero border = conv2 padding
  prep_w2_kern<<<dim3(10, 1024), 256, 0, stream>>>(w2, g2, v2, w2bf);
  prep_small_kern<<<2400, 256, 0, stream>>>(meta, g2, b2, m2, v2, clsw, clsb, shift2);
  conv1_reorg_kern<<<dim3(181, 2), 256, 0, stream>>>(stage5, w1, g1, b1, m1, v1, in_bf);
  fill_stage6_kern<<<dim3(6, 16, 32), 256, 0, stream>>>(stage6, in_bf);
  conv2_gemm_kern<<<dim3(91, 8), 256, 0, stream>>>(w2bf, in_bf, shift2, prebf);
  einsum_gemm_kern<<<dim3(91, 5), 256, 0, stream>>>(clsw, prebf, clsb, out);
}

// Round 4
// 704.252 us; speedup vs baseline: 1.2764x; 1.2764x over previous
//
#include <hip/hip_runtime.h>

typedef unsigned short u16;
typedef unsigned int   u32;

typedef __attribute__((ext_vector_type(8))) short bf16x8;
typedef __attribute__((ext_vector_type(4))) float f32x4;

__device__ __forceinline__ u16 f2bf(float f) {
  u32 u = __float_as_uint(f);
  u32 r = (u + 0x7fffu + ((u >> 16) & 1u)) >> 16;
  return (u16)r;
}

__device__ __forceinline__ void async16(const void* g, void* l) {
  __builtin_amdgcn_global_load_lds(
      (const __attribute__((address_space(1))) u32*)g,
      (__attribute__((address_space(3))) u32*)l, 16, 0, 0);
}

// ---------------------------------------------------------------------------
// conv1 (1x1, 512->64) + BN + leaky + reorg, writes in_bf channels [0,256)
// ---------------------------------------------------------------------------
__global__ __launch_bounds__(256) void conv1_reorg_kern(
    const float* __restrict__ stage5, const float* __restrict__ w1,
    const float* __restrict__ g1, const float* __restrict__ b1,
    const float* __restrict__ m1, const float* __restrict__ v1,
    u16* __restrict__ in_bf)
{
  __shared__ float wlds[64][40];
  __shared__ float2 bn[32];
  const int t = threadIdx.x;
  const int ocb = blockIdx.y * 32;
  int m = blockIdx.x * 256 + t;
  bool valid = (m < 46208);
  int mm = valid ? m : 46207;
  int b = mm / 1444;
  int hw = mm - b * 1444;
  const float* src = stage5 + (size_t)b * (512 * 1444) + hw;
  if (t < 32) {
    float sc = g1[ocb + t] * rsqrtf(v1[ocb + t] + 1e-5f);
    bn[t].x = sc;
    bn[t].y = b1[ocb + t] - m1[ocb + t] * sc;
  }
  float acc[32];
#pragma unroll
  for (int i = 0; i < 32; ++i) acc[i] = 0.f;

  for (int ic0 = 0; ic0 < 512; ic0 += 64) {
    __syncthreads();
#pragma unroll
    for (int r = 0; r < 8; ++r) {
      int idx = r * 256 + t;
      int oc_l = idx >> 6, icl = idx & 63;
      wlds[icl][oc_l] = w1[(size_t)(ocb + oc_l) * 512 + ic0 + icl];
    }
    __syncthreads();
    for (int g = 0; g < 4; ++g) {
      float av[16];
#pragma unroll
      for (int u = 0; u < 16; ++u)
        av[u] = src[(size_t)(ic0 + g * 16 + u) * 1444];
#pragma unroll
      for (int u = 0; u < 16; ++u) {
#pragma unroll
        for (int o4 = 0; o4 < 8; ++o4) {
          float4 wv = *(const float4*)&wlds[g * 16 + u][o4 * 4];
          acc[o4 * 4 + 0] += av[u] * wv.x;
          acc[o4 * 4 + 1] += av[u] * wv.y;
          acc[o4 * 4 + 2] += av[u] * wv.z;
          acc[o4 * 4 + 3] += av[u] * wv.w;
        }
      }
    }
  }
  if (valid) {
    int h = hw / 38, wq = hw - h * 38;
    int ho = h >> 1, wo = wq >> 1, q = ((h & 1) << 1) | (wq & 1);
    u16* dst = in_bf + (((size_t)b * 21 + 1 + ho) * 21 + 1 + wo) * 1280 + q * 64 + ocb;
#pragma unroll
    for (int gg = 0; gg < 8; ++gg) {
      int oc = gg * 4;
      float v0 = acc[oc + 0] * bn[oc + 0].x + bn[oc + 0].y;
      float v1 = acc[oc + 1] * bn[oc + 1].x + bn[oc + 1].y;
      float v2 = acc[oc + 2] * bn[oc + 2].x + bn[oc + 2].y;
      float v3 = acc[oc + 3] * bn[oc + 3].x + bn[oc + 3].y;
      v0 = v0 > 0.f ? v0 : 0.1f * v0;
      v1 = v1 > 0.f ? v1 : 0.1f * v1;
      v2 = v2 > 0.f ? v2 : 0.1f * v2;
      v3 = v3 > 0.f ? v3 : 0.1f * v3;
      u32 lo = (u32)f2bf(v0) | ((u32)f2bf(v1) << 16);
      u32 hi = (u32)f2bf(v2) | ((u32)f2bf(v3) << 16);
      u32* dp = (u32*)(dst + oc);
      dp[0] = lo; dp[1] = hi;
    }
  }
}

// ---------------------------------------------------------------------------
// stage6 NCHW -> in_bf NHWC channels [256,1280), bf16, LDS-tiled transpose
// ---------------------------------------------------------------------------
__global__ __launch_bounds__(256) void fill_stage6_kern(
    const float* __restrict__ s6, u16* __restrict__ in_bf)
{
  __shared__ u16 tile[64][66];
  const int t = threadIdx.x;
  const int jt = blockIdx.x, ct = blockIdx.y, b = blockIdx.z;
  const int ij0 = jt * 64, c0 = ct * 64;
  const int col = t & 63, rr = t >> 6;
#pragma unroll
  for (int r = 0; r < 16; ++r) {
    int cl = r * 4 + rr;
    int ij = ij0 + col;
    float v = 0.f;
    if (ij < 361) v = s6[((size_t)b * 1024 + c0 + cl) * 361 + ij];
    tile[cl][col] = f2bf(v);
  }
  __syncthreads();
#pragma unroll
  for (int r = 0; r < 16; ++r) {
    int ijl = r * 4 + rr;
    int ij = ij0 + ijl;
    if (ij < 361) {
      int i = ij / 19, j = ij - i * 19;
      in_bf[(((size_t)b * 21 + 1 + i) * 21 + 1 + j) * 1280 + 256 + c0 + col] =
          tile[col][ijl];
    }
  }
}

// ---------------------------------------------------------------------------
// w2 -> PACKED staging layout Wp[(octile*360+kc)*8+g][lane]:
//   entry lane l = W[octile*128 + g*16 + (l&15)][kc*32 + (l>>4)*8 .. +8]
// so conv2's wave-staging read is contiguous 1KB AND the LDS image is the
// linear (lane*16B) conflict-free layout. BN scale folded.
// block = (icb 0..9, oc 0..1023); coalesced 1152-float read, LDS transpose.
// ---------------------------------------------------------------------------
__global__ __launch_bounds__(256) void prep_w2_kern(
    const float* __restrict__ w2, const float* __restrict__ g2,
    const float* __restrict__ v2, u16* __restrict__ w2p)
{
  __shared__ u16 tile[9 * 130];    // [khw][ic_l]
  const int t = threadIdx.x;
  const int icb = blockIdx.x;      // 0..9
  const int oc = blockIdx.y;       // 0..1023
  const int ic0 = icb * 128;
  const float sc = g2[oc] * rsqrtf(v2[oc] + 1e-5f);
  const float* src = w2 + (size_t)oc * 11520 + (size_t)ic0 * 9;
#pragma unroll
  for (int p = t; p < 1152; p += 256) {
    float v = src[p];
    int ic_l = p / 9;
    int khw = p - ic_l * 9;
    tile[khw * 130 + ic_l] = f2bf(v * sc);
  }
  __syncthreads();
  // 144 granules of 16B: (khw 0..8) x (c 0..3) x (ksub 0..3)
  if (t < 144) {
    int khw = t >> 4, c = (t >> 2) & 3, ksub = t & 3;
    int kc = khw * 40 + icb * 4 + c;
    const u16* s = &tile[khw * 130 + c * 32 + ksub * 8];
    uint4 v;
    v.x = (u32)s[0] | ((u32)s[1] << 16);
    v.y = (u32)s[2] | ((u32)s[3] << 16);
    v.z = (u32)s[4] | ((u32)s[5] << 16);
    v.w = (u32)s[6] | ((u32)s[7] << 16);
    size_t dst = (((size_t)(oc >> 7) * 360 + kc) * 8 + ((oc >> 4) & 7)) * 512
                 + (size_t)(ksub * 16 + (oc & 15)) * 8;
    *(uint4*)(w2p + dst) = v;
  }
}

// ---------------------------------------------------------------------------
// meta_state -> cls_w PACKED (same staging layout, 5 cm-tiles x 32 kc),
// cls_b fp32 [600]; shift2 fp32 [1024]
// ---------------------------------------------------------------------------
__global__ __launch_bounds__(256) void prep_small_kern(
    const float* __restrict__ meta, const float* __restrict__ g2,
    const float* __restrict__ b2, const float* __restrict__ m2,
    const float* __restrict__ v2, u16* __restrict__ clsp,
    float* __restrict__ clsb, float* __restrict__ shift2)
{
  int idx = blockIdx.x * 256 + threadIdx.x;   // 614400 threads = 600cm x 1024k
  int cm = idx >> 10, k = idx & 1023;
  int tile = cm >> 7, g = (cm >> 4) & 7, mm = cm & 15;
  int kc = k >> 5, ksub = (k >> 3) & 3, e = k & 7;
  size_t dst = (((size_t)tile * 32 + kc) * 8 + g) * 512
               + (size_t)(ksub * 16 + mm) * 8 + e;
  clsp[dst] = f2bf(meta[(size_t)cm * 1025 + k]);
  if (idx < 600) clsb[idx] = meta[(size_t)idx * 1025 + 1024];
  if (idx < 1024) {
    float sc = g2[idx] * rsqrtf(v2[idx] + 1e-5f);
    shift2[idx] = b2[idx] - m2[idx] * sc;
  }
}

// ---------------------------------------------------------------------------
// conv2: implicit GEMM, 128(oc) x 128(m) x 32-k tiles, 16x16x32 bf16 MFMA.
// A (W): packed global layout -> contiguous 1KB wave reads, linear LDS,
//        zero-conflict A-fragment reads (addr = lane*16B).
// B (I): coalesced staging (4 lanes/pixel-row, 64B segments) with XOR-swizzled
//        ksub: lane l stages ksub=(l&3)^((l>>3)&3). Quarter-wave B-fragment
//        reads then cover all 8 bank-quads 2x = conflict-free (m136: 2-way free).
// XCD swizzle: oc_tile = lin&7 keeps one 2.95MB W slice per XCD L2.
// ---------------------------------------------------------------------------
__global__ __launch_bounds__(256) void conv2_gemm_kern(
    const u16* __restrict__ Wp, const u16* __restrict__ Ig,
    const float* __restrict__ shift2, u16* __restrict__ pre)
{
  __shared__ u16 Wa[128 * 32];
  __shared__ u16 Ib[128 * 32];
  __shared__ float shft[128];
  const int t = threadIdx.x;
  const int w = t >> 6, lane = t & 63;
  const int lin = blockIdx.x + 91 * blockIdx.y;
  const int m0 = (lin >> 3) * 128;
  const int oc0 = (lin & 7) * 128;

  if (t < 128) shft[t] = shift2[oc0 + t];

  // A: packed; wave w covers row-groups g=w (rows 16w..) and g=4+w
  const u16* pW0 = Wp + ((size_t)(oc0 >> 7) * 2880 + w) * 512 + lane * 8;
  // per kc: offset kc*4096 ; second group: +2048

  // B: coalesced + swizzle
  const int rw = t >> 2;                               // pixel-row 0..63
  const int rpart = ((t & 3) ^ ((t >> 3) & 3)) * 8;    // swizzled ksub
  int mA = m0 + rw;       if (mA > 11551) mA = 11551;
  int mB = m0 + 64 + rw;  if (mB > 11551) mB = 11551;
  int bA = mA / 361, ijA = mA - bA * 361;
  int ohA = ijA / 19, owA = ijA - ohA * 19;
  int bB = mB / 361, ijB = mB - bB * 361;
  int ohB = ijB / 19, owB = ijB - ohB * 19;
  const u16* pI0 = Ig + (size_t)((bA * 21 + ohA) * 21 + owA) * 1280 + rpart;
  const u16* pI1 = Ig + (size_t)((bB * 21 + ohB) * 21 + owB) * 1280 + rpart;

  u16* waS0 = &Wa[w * 512];
  u16* waS1 = &Wa[2048 + w * 512];
  u16* ibS0 = &Ib[w * 512];
  u16* ibS1 = &Ib[2048 + w * 512];

  const int aBase = (w >> 1) * 2048 + lane * 8;
  const int bBase = (w & 1) * 2048 + (lane & 15) * 32 +
                    (((lane >> 4) ^ ((lane >> 1) & 3))) * 8;

  f32x4 acc[4][4] = {};

  for (int khw = 0; khw < 9; ++khw) {
    const int kh = khw / 3, kw = khw - kh * 3;
    const size_t iOffB = (size_t)(kh * 21 + kw) * 1280;
    const size_t wOffB = (size_t)khw * 40 * 4096;
    for (int icc = 0; icc < 40; ++icc) {
      const size_t io = iOffB + (size_t)icc * 32;
      const size_t wo_ = wOffB + (size_t)icc * 4096;
      async16(pW0 + wo_, waS0);
      async16(pW0 + wo_ + 2048, waS1);
      async16(pI0 + io, ibS0);
      async16(pI1 + io, ibS1);
      __syncthreads();
      bf16x8 af[4], bfv[4];
#pragma unroll
      for (int i = 0; i < 4; ++i)
        af[i] = *(const bf16x8*)&Wa[aBase + i * 512];
#pragma unroll
      for (int j = 0; j < 4; ++j)
        bfv[j] = *(const bf16x8*)&Ib[bBase + j * 512];
#pragma unroll
      for (int i = 0; i < 4; ++i)
#pragma unroll
        for (int j = 0; j < 4; ++j)
          acc[i][j] = __builtin_amdgcn_mfma_f32_16x16x32_bf16(
              af[i], bfv[j], acc[i][j], 0, 0, 0);
      __syncthreads();
    }
  }

  const int aRow = (w >> 1) * 64, bRow = (w & 1) * 64;
  const int lq = lane >> 4, lr = lane & 15;
#pragma unroll
  for (int j = 0; j < 4; ++j) {
    int m = m0 + bRow + j * 16 + lr;
    if (m >= 11552) continue;
    u16* prow = pre + (size_t)m * 1024 + oc0;
#pragma unroll
    for (int i = 0; i < 4; ++i) {
      int ocl = aRow + i * 16 + lq * 4;
      float v0 = acc[i][j][0] + shft[ocl + 0]; v0 = v0 > 0.f ? v0 : 0.1f * v0;
      float v1 = acc[i][j][1] + shft[ocl + 1]; v1 = v1 > 0.f ? v1 : 0.1f * v1;
      float v2 = acc[i][j][2] + shft[ocl + 2]; v2 = v2 > 0.f ? v2 : 0.1f * v2;
      float v3 = acc[i][j][3] + shft[ocl + 3]; v3 = v3 > 0.f ? v3 : 0.1f * v3;
      u32 lo = (u32)f2bf(v0) | ((u32)f2bf(v1) << 16);
      u32 hi = (u32)f2bf(v2) | ((u32)f2bf(v3) << 16);
      u32* dp = (u32*)(prow + ocl);
      dp[0] = lo; dp[1] = hi;
    }
  }
}

// ---------------------------------------------------------------------------
// einsum: GEMM A=cls_w packed [5 tiles x 32 kc], B=pre[11552][1024].
// Same A-pack / B-swizzle scheme as conv2. out fp32 + bias, scatter.
// ---------------------------------------------------------------------------
__global__ __launch_bounds__(256) void einsum_gemm_kern(
    const u16* __restrict__ Ap, const u16* __restrict__ Bg,
    const float* __restrict__ biasg, float* __restrict__ out)
{
  __shared__ u16 Wa[128 * 32];
  __shared__ u16 Ib[128 * 32];
  __shared__ float sbias[128];
  const int t = threadIdx.x;
  const int w = t >> 6, lane = t & 63;
  const int m0 = blockIdx.x * 128;
  const int cm0 = blockIdx.y * 128;
  if (t < 128) { int c = cm0 + t; sbias[t] = (c < 600) ? biasg[c] : 0.f; }

  const u16* pA0 = Ap + ((size_t)(cm0 >> 7) * 256 + w) * 512 + lane * 8;
  // per kt: + kt*4096 ; second group +2048

  const int rw = t >> 2;
  const int rpart = ((t & 3) ^ ((t >> 3) & 3)) * 8;
  int rB0 = m0 + rw;        if (rB0 > 11551) rB0 = 11551;
  int rB1 = m0 + 64 + rw;   if (rB1 > 11551) rB1 = 11551;
  const u16* pB0 = Bg + (size_t)rB0 * 1024 + rpart;
  const u16* pB1 = Bg + (size_t)rB1 * 1024 + rpart;

  u16* waS0 = &Wa[w * 512];
  u16* waS1 = &Wa[2048 + w * 512];
  u16* ibS0 = &Ib[w * 512];
  u16* ibS1 = &Ib[2048 + w * 512];

  const int aBase = (w >> 1) * 2048 + lane * 8;
  const int bBase = (w & 1) * 2048 + (lane & 15) * 32 +
                    (((lane >> 4) ^ ((lane >> 1) & 3))) * 8;

  f32x4 acc[4][4] = {};

  for (int kt = 0; kt < 32; ++kt) {
    const size_t off = (size_t)kt * 32;
    async16(pA0 + (size_t)kt * 4096, waS0);
    async16(pA0 + (size_t)kt * 4096 + 2048, waS1);
    async16(pB0 + off, ibS0);
    async16(pB1 + off, ibS1);
    __syncthreads();
    bf16x8 af[4], bfv[4];
#pragma unroll
    for (int i = 0; i < 4; ++i)
      af[i] = *(const bf16x8*)&Wa[aBase + i * 512];
#pragma unroll
    for (int j = 0; j < 4; ++j)
      bfv[j] = *(const bf16x8*)&Ib[bBase + j * 512];
#pragma unroll
    for (int i = 0; i < 4; ++i)
#pragma unroll
      for (int j = 0; j < 4; ++j)
        acc[i][j] = __builtin_amdgcn_mfma_f32_16x16x32_bf16(
            af[i], bfv[j], acc[i][j], 0, 0, 0);
    __syncthreads();
  }

  const int aRow = (w >> 1) * 64, bRow = (w & 1) * 64;
  const int lq = lane >> 4, lr = lane & 15;
#pragma unroll
  for (int j = 0; j < 4; ++j) {
    int m = m0 + bRow + j * 16 + lr;
    if (m >= 11552) continue;
    int b = m / 361, ij = m - b * 361;
    float* obase = out + (size_t)b * 216600 + ij;
#pragma unroll
    for (int i = 0; i < 4; ++i) {
      int cml = aRow + i * 16 + lq * 4;
#pragma unroll
      for (int r = 0; r < 4; ++r) {
        int cm = cm0 + cml + r;
        if (cm < 600) obase[(size_t)cm * 361] = acc[i][j][r] + sbias[cml + r];
      }
    }
  }
}

// ---------------------------------------------------------------------------
// launch
// ---------------------------------------------------------------------------
extern "C" void kernel_launch(void* const* d_in, const int* in_sizes, int n_in,
                              void* d_out, int out_size, void* d_ws, size_t ws_size,
                              hipStream_t stream)
{
  const float* stage6 = (const float*)d_in[0];
  const float* stage5 = (const float*)d_in[1];
  const float* w1 = (const float*)d_in[2];
  const float* g1 = (const float*)d_in[3];
  const float* b1 = (const float*)d_in[4];
  const float* m1 = (const float*)d_in[5];
  const float* v1 = (const float*)d_in[6];
  const float* w2 = (const float*)d_in[7];
  const float* g2 = (const float*)d_in[8];
  const float* b2 = (const float*)d_in[9];
  const float* m2 = (const float*)d_in[10];
  const float* v2 = (const float*)d_in[11];
  const float* meta = (const float*)d_in[12];
  float* out = (float*)d_out;

  char* ws = (char*)d_ws;
  u16*   in_bf  = (u16*)(ws);                  // 36,126,720 B  (32*21*21*1280 bf16)
  u16*   w2p    = (u16*)(ws + 36126720);       // 23,592,960 B  packed W
  u16*   prebf  = (u16*)(ws + 59719680);       // 23,658,496 B  (11552*1024 bf16)
  u16*   clsp   = (u16*)(ws + 83378176);       //  1,310,720 B  packed cls_w (5 tiles)
  float* clsb   = (float*)(ws + 84688896);     //      2,560 B
  float* shift2 = (float*)(ws + 84691456);     //      4,096 B   total ~84.7 MB

  hipMemsetAsync(in_bf, 0, 36126720, stream);  // zero border = conv2 padding
  prep_w2_kern<<<dim3(10, 1024), 256, 0, stream>>>(w2, g2, v2, w2p);
  prep_small_kern<<<2400, 256, 0, stream>>>(meta, g2, b2, m2, v2, clsp, clsb, shift2);
  conv1_reorg_kern<<<dim3(181, 2), 256, 0, stream>>>(stage5, w1, g1, b1, m1, v1, in_bf);
  fill_stage6_kern<<<dim3(6, 16, 32), 256, 0, stream>>>(stage6, in_bf);
  conv2_gemm_kern<<<dim3(91, 8), 256, 0, stream>>>(w2p, in_bf, shift2, prebf);
  einsum_gemm_kern<<<dim3(91, 5), 256, 0, stream>>>(clsp, prebf, clsb, out);
}

// Round 5
// 600.623 us; speedup vs baseline: 1.4966x; 1.1725x over previous
//
#include <hip/hip_runtime.h>

typedef unsigned short u16;
typedef unsigned int   u32;

typedef __attribute__((ext_vector_type(8))) short bf16x8;
typedef __attribute__((ext_vector_type(4))) float f32x4;

__device__ __forceinline__ u16 f2bf(float f) {
  u32 u = __float_as_uint(f);
  u32 r = (u + 0x7fffu + ((u >> 16) & 1u)) >> 16;
  return (u16)r;
}

__device__ __forceinline__ void async16(const void* g, void* l) {
  __builtin_amdgcn_global_load_lds(
      (const __attribute__((address_space(1))) u32*)g,
      (__attribute__((address_space(3))) u32*)l, 16, 0, 0);
}

// ---------------------------------------------------------------------------
// mega_prep: all pre-conv2 work in ONE launch (independent block-range tasks):
//   [0,722)       conv1 as MFMA GEMM (64oc x 64pix x K=512), fused NCHW->LDS
//   [722,3794)    stage6 NCHW -> in_bf NHWC ch[256,1280) transpose
//   [3794,5394)   border zero (replaces 36MB memset; interior fully written)
//   [5394,7794)   meta -> clsp packed + clsb + shift2
//   [7794,18034)  w2 -> w2p packed staging layout, BN scale folded
// ---------------------------------------------------------------------------
__global__ __launch_bounds__(256) void mega_prep_kern(
    const float* __restrict__ stage5, const float* __restrict__ s6,
    const float* __restrict__ w1,
    const float* __restrict__ g1, const float* __restrict__ b1,
    const float* __restrict__ m1, const float* __restrict__ v1,
    const float* __restrict__ w2, const float* __restrict__ g2,
    const float* __restrict__ b2, const float* __restrict__ m2,
    const float* __restrict__ v2, const float* __restrict__ meta,
    u16* __restrict__ in_bf, u16* __restrict__ w2p,
    u16* __restrict__ clsp, float* __restrict__ clsb,
    float* __restrict__ shift2)
{
  __shared__ __align__(16) char smem[8704];
  const int bid = blockIdx.x;
  const int t = threadIdx.x;

  if (bid < 722) {
    // ---- conv1: MFMA GEMM, A=w1 (64x512, scale-folded), B=stage5 pixels ----
    float* sc_s = (float*)smem;           // 64 scales
    float* sh_s = (float*)(smem + 256);   // 64 shifts
    char*  aT   = smem + 512;             // 64x32 bf16 = 4096 B
    char*  bT   = smem + 4608;            // 64x32 bf16 = 4096 B
    const int w = t >> 6, lane = t & 63;
    if (t < 64) {
      float s = g1[t] * rsqrtf(v1[t] + 1e-5f);
      sc_s[t] = s;
      sh_s[t] = b1[t] - m1[t] * s;
    }
    const int m0 = bid * 64;              // 722*64 = 46208 exact, no tail
    const int pS = t & 63, gS = t >> 6;   // staged pixel, k-granule
    const int mS = m0 + pS;
    const int bS = mS / 1444, hwS = mS - bS * 1444;
    const float* s5 = stage5 + (size_t)bS * (512 * 1444) + hwS;
    const int ocA = t >> 2, icqA = t & 3; // A staging: 4 threads/oc-row
    const float* w1r = w1 + (size_t)ocA * 512 + icqA * 8;
    char* aW = aT + (ocA >> 4) * 1024 + (icqA * 16 + (ocA & 15)) * 16;
    char* bW = bT + pS * 64 + ((gS ^ ((pS >> 1) & 3))) * 16;
    const int bR = (w * 16 + (lane & 15)) * 64 +
                   (((lane >> 4) ^ (((lane & 15) >> 1) & 3))) * 16;
    f32x4 acc[4] = {};
    __syncthreads();
    const float sA = sc_s[ocA];
    for (int kc = 0; kc < 16; ++kc) {
      const int ic0 = kc * 32;
      float a8[8], b8[8];
#pragma unroll
      for (int e = 0; e < 8; ++e) a8[e] = w1r[ic0 + e];
#pragma unroll
      for (int e = 0; e < 8; ++e) b8[e] = s5[(size_t)(ic0 + gS * 8 + e) * 1444];
      __syncthreads();   // previous iter's LDS reads complete
      uint4 av, bv;
      av.x = (u32)f2bf(a8[0] * sA) | ((u32)f2bf(a8[1] * sA) << 16);
      av.y = (u32)f2bf(a8[2] * sA) | ((u32)f2bf(a8[3] * sA) << 16);
      av.z = (u32)f2bf(a8[4] * sA) | ((u32)f2bf(a8[5] * sA) << 16);
      av.w = (u32)f2bf(a8[6] * sA) | ((u32)f2bf(a8[7] * sA) << 16);
      bv.x = (u32)f2bf(b8[0]) | ((u32)f2bf(b8[1]) << 16);
      bv.y = (u32)f2bf(b8[2]) | ((u32)f2bf(b8[3]) << 16);
      bv.z = (u32)f2bf(b8[4]) | ((u32)f2bf(b8[5]) << 16);
      bv.w = (u32)f2bf(b8[6]) | ((u32)f2bf(b8[7]) << 16);
      *(uint4*)aW = av;
      *(uint4*)bW = bv;
      __syncthreads();
      bf16x8 bfv = *(const bf16x8*)(bT + bR);
#pragma unroll
      for (int i = 0; i < 4; ++i) {
        bf16x8 af = *(const bf16x8*)(aT + i * 1024 + lane * 16);
        acc[i] = __builtin_amdgcn_mfma_f32_16x16x32_bf16(af, bfv, acc[i], 0, 0, 0);
      }
    }
    const int mE = m0 + w * 16 + (lane & 15);
    const int bE = mE / 1444, hwE = mE - bE * 1444;
    const int h = hwE / 38, wq = hwE - h * 38;
    const int ho = h >> 1, wo = wq >> 1, q = ((h & 1) << 1) | (wq & 1);
    u16* dst = in_bf + (((size_t)bE * 21 + 1 + ho) * 21 + 1 + wo) * 1280 + q * 64;
    const int lq = lane >> 4;
#pragma unroll
    for (int i = 0; i < 4; ++i) {
      int oc = i * 16 + lq * 4;
      float v0 = acc[i][0] + sh_s[oc + 0]; v0 = v0 > 0.f ? v0 : 0.1f * v0;
      float v1_ = acc[i][1] + sh_s[oc + 1]; v1_ = v1_ > 0.f ? v1_ : 0.1f * v1_;
      float v2_ = acc[i][2] + sh_s[oc + 2]; v2_ = v2_ > 0.f ? v2_ : 0.1f * v2_;
      float v3 = acc[i][3] + sh_s[oc + 3]; v3 = v3 > 0.f ? v3 : 0.1f * v3;
      u32 lo = (u32)f2bf(v0) | ((u32)f2bf(v1_) << 16);
      u32 hi = (u32)f2bf(v2_) | ((u32)f2bf(v3) << 16);
      u32* dp = (u32*)(dst + oc);
      dp[0] = lo; dp[1] = hi;
    }
    return;
  }

  if (bid < 3794) {
    // ---- stage6 NCHW -> in_bf NHWC [256,1280) ----
    u16 (*tile)[66] = (u16(*)[66])smem;   // 64x66 u16 = 8448 B
    const int sub = bid - 722;
    const int jt = sub % 6, ct = (sub / 6) % 16, b = sub / 96;
    const int ij0 = jt * 64, c0 = ct * 64;
    const int col = t & 63, rr = t >> 6;
#pragma unroll
    for (int r = 0; r < 16; ++r) {
      int cl = r * 4 + rr;
      int ij = ij0 + col;
      float v = 0.f;
      if (ij < 361) v = s6[((size_t)b * 1024 + c0 + cl) * 361 + ij];
      tile[cl][col] = f2bf(v);
    }
    __syncthreads();
#pragma unroll
    for (int r = 0; r < 16; ++r) {
      int ijl = r * 4 + rr;
      int ij = ij0 + ijl;
      if (ij < 361) {
        int i = ij / 19, j = ij - i * 19;
        in_bf[(((size_t)b * 21 + 1 + i) * 21 + 1 + j) * 1280 + 256 + c0 + col] =
            tile[col][ijl];
      }
    }
    return;
  }

  if (bid < 5394) {
    // ---- border zero: 32 b x 80 border pixels x 1280 ch, 16B per thread ----
    int gi = (bid - 3794) * 256 + t;      // [0, 409600) exact
    int b = gi / 12800;
    int rem = gi - b * 12800;
    int p = rem / 160, qq = rem - p * 160;
    int row, col;
    if (p < 21)      { row = 0;      col = p; }
    else if (p < 42) { row = 20;     col = p - 21; }
    else if (p < 61) { row = p - 41; col = 0; }
    else             { row = p - 60; col = 20; }
    uint4 z = {0u, 0u, 0u, 0u};
    *(uint4*)(in_bf + (((size_t)b * 21 + row) * 21 + col) * 1280 + qq * 8) = z;
    return;
  }

  if (bid < 7794) {
    // ---- meta -> clsp packed + clsb; shift2 ----
    int idx = (bid - 5394) * 256 + t;     // 614400 = 600cm x 1024k
    int cm = idx >> 10, k = idx & 1023;
    int tile_ = cm >> 7, g = (cm >> 4) & 7, mm = cm & 15;
    int kc = k >> 5, ksub = (k >> 3) & 3, e = k & 7;
    size_t dst = (((size_t)tile_ * 32 + kc) * 8 + g) * 512
                 + (size_t)(ksub * 16 + mm) * 8 + e;
    clsp[dst] = f2bf(meta[(size_t)cm * 1025 + k]);
    if (idx < 600) clsb[idx] = meta[(size_t)idx * 1025 + 1024];
    if (idx < 1024) {
      float sc = g2[idx] * rsqrtf(v2[idx] + 1e-5f);
      shift2[idx] = b2[idx] - m2[idx] * sc;
    }
    return;
  }

  {
    // ---- w2 -> w2p packed staging layout, BN scale folded ----
    u16* tile = (u16*)smem;               // 9*130 u16 = 2340 B
    const int sub = bid - 7794;           // [0, 10240)
    const int icb = sub % 10;
    const int oc = sub / 10;
    const int ic0 = icb * 128;
    const float sc = g2[oc] * rsqrtf(v2[oc] + 1e-5f);
    const float* src = w2 + (size_t)oc * 11520 + (size_t)ic0 * 9;
#pragma unroll
    for (int p = t; p < 1152; p += 256) {
      float v = src[p];
      int ic_l = p / 9;
      int khw = p - ic_l * 9;
      tile[khw * 130 + ic_l] = f2bf(v * sc);
    }
    __syncthreads();
    if (t < 144) {
      int khw = t >> 4, c = (t >> 2) & 3, ksub = t & 3;
      int kc = khw * 40 + icb * 4 + c;
      const u16* s = &tile[khw * 130 + c * 32 + ksub * 8];
      uint4 v;
      v.x = (u32)s[0] | ((u32)s[1] << 16);
      v.y = (u32)s[2] | ((u32)s[3] << 16);
      v.z = (u32)s[4] | ((u32)s[5] << 16);
      v.w = (u32)s[6] | ((u32)s[7] << 16);
      size_t dst = (((size_t)(oc >> 7) * 360 + kc) * 8 + ((oc >> 4) & 7)) * 512
                   + (size_t)(ksub * 16 + (oc & 15)) * 8;
      *(uint4*)(w2p + dst) = v;
    }
  }
}

// ---------------------------------------------------------------------------
// conv2: implicit GEMM, 128(oc) x 128(m) x 32-k tiles, 16x16x32 bf16 MFMA.
// A (W): packed global layout -> contiguous 1KB wave reads, linear LDS,
//        zero-conflict A-fragment reads. B (I): coalesced + XOR-swizzled ksub.
// (proven r4: 328 us, MfmaUtil 37.6%, conflicts 0 — frozen)
// ---------------------------------------------------------------------------
__global__ __launch_bounds__(256) void conv2_gemm_kern(
    const u16* __restrict__ Wp, const u16* __restrict__ Ig,
    const float* __restrict__ shift2, u16* __restrict__ pre)
{
  __shared__ u16 Wa[128 * 32];
  __shared__ u16 Ib[128 * 32];
  __shared__ float shft[128];
  const int t = threadIdx.x;
  const int w = t >> 6, lane = t & 63;
  const int lin = blockIdx.x + 91 * blockIdx.y;
  const int m0 = (lin >> 3) * 128;
  const int oc0 = (lin & 7) * 128;

  if (t < 128) shft[t] = shift2[oc0 + t];

  const u16* pW0 = Wp + ((size_t)(oc0 >> 7) * 2880 + w) * 512 + lane * 8;

  const int rw = t >> 2;
  const int rpart = ((t & 3) ^ ((t >> 3) & 3)) * 8;
  int mA = m0 + rw;       if (mA > 11551) mA = 11551;
  int mB = m0 + 64 + rw;  if (mB > 11551) mB = 11551;
  int bA = mA / 361, ijA = mA - bA * 361;
  int ohA = ijA / 19, owA = ijA - ohA * 19;
  int bB = mB / 361, ijB = mB - bB * 361;
  int ohB = ijB / 19, owB = ijB - ohB * 19;
  const u16* pI0 = Ig + (size_t)((bA * 21 + ohA) * 21 + owA) * 1280 + rpart;
  const u16* pI1 = Ig + (size_t)((bB * 21 + ohB) * 21 + owB) * 1280 + rpart;

  u16* waS0 = &Wa[w * 512];
  u16* waS1 = &Wa[2048 + w * 512];
  u16* ibS0 = &Ib[w * 512];
  u16* ibS1 = &Ib[2048 + w * 512];

  const int aBase = (w >> 1) * 2048 + lane * 8;
  const int bBase = (w & 1) * 2048 + (lane & 15) * 32 +
                    (((lane >> 4) ^ ((lane >> 1) & 3))) * 8;

  f32x4 acc[4][4] = {};

  for (int khw = 0; khw < 9; ++khw) {
    const int kh = khw / 3, kw = khw - kh * 3;
    const size_t iOffB = (size_t)(kh * 21 + kw) * 1280;
    const size_t wOffB = (size_t)khw * 40 * 4096;
    for (int icc = 0; icc < 40; ++icc) {
      const size_t io = iOffB + (size_t)icc * 32;
      const size_t wo_ = wOffB + (size_t)icc * 4096;
      async16(pW0 + wo_, waS0);
      async16(pW0 + wo_ + 2048, waS1);
      async16(pI0 + io, ibS0);
      async16(pI1 + io, ibS1);
      __syncthreads();
      bf16x8 af[4], bfv[4];
#pragma unroll
      for (int i = 0; i < 4; ++i)
        af[i] = *(const bf16x8*)&Wa[aBase + i * 512];
#pragma unroll
      for (int j = 0; j < 4; ++j)
        bfv[j] = *(const bf16x8*)&Ib[bBase + j * 512];
#pragma unroll
      for (int i = 0; i < 4; ++i)
#pragma unroll
        for (int j = 0; j < 4; ++j)
          acc[i][j] = __builtin_amdgcn_mfma_f32_16x16x32_bf16(
              af[i], bfv[j], acc[i][j], 0, 0, 0);
      __syncthreads();
    }
  }

  const int aRow = (w >> 1) * 64, bRow = (w & 1) * 64;
  const int lq = lane >> 4, lr = lane & 15;
#pragma unroll
  for (int j = 0; j < 4; ++j) {
    int m = m0 + bRow + j * 16 + lr;
    if (m >= 11552) continue;
    u16* prow = pre + (size_t)m * 1024 + oc0;
#pragma unroll
    for (int i = 0; i < 4; ++i) {
      int ocl = aRow + i * 16 + lq * 4;
      float v0 = acc[i][j][0] + shft[ocl + 0]; v0 = v0 > 0.f ? v0 : 0.1f * v0;
      float v1 = acc[i][j][1] + shft[ocl + 1]; v1 = v1 > 0.f ? v1 : 0.1f * v1;
      float v2 = acc[i][j][2] + shft[ocl + 2]; v2 = v2 > 0.f ? v2 : 0.1f * v2;
      float v3 = acc[i][j][3] + shft[ocl + 3]; v3 = v3 > 0.f ? v3 : 0.1f * v3;
      u32 lo = (u32)f2bf(v0) | ((u32)f2bf(v1) << 16);
      u32 hi = (u32)f2bf(v2) | ((u32)f2bf(v3) << 16);
      u32* dp = (u32*)(prow + ocl);
      dp[0] = lo; dp[1] = hi;
    }
  }
}

// ---------------------------------------------------------------------------
// einsum: GEMM A=cls_w packed [5 tiles x 32 kc], B=pre[11552][1024].
// Same A-pack / B-swizzle scheme as conv2. out fp32 + bias, scatter.
// ---------------------------------------------------------------------------
__global__ __launch_bounds__(256) void einsum_gemm_kern(
    const u16* __restrict__ Ap, const u16* __restrict__ Bg,
    const float* __restrict__ biasg, float* __restrict__ out)
{
  __shared__ u16 Wa[128 * 32];
  __shared__ u16 Ib[128 * 32];
  __shared__ float sbias[128];
  const int t = threadIdx.x;
  const int w = t >> 6, lane = t & 63;
  const int m0 = blockIdx.x * 128;
  const int cm0 = blockIdx.y * 128;
  if (t < 128) { int c = cm0 + t; sbias[t] = (c < 600) ? biasg[c] : 0.f; }

  const u16* pA0 = Ap + ((size_t)(cm0 >> 7) * 256 + w) * 512 + lane * 8;

  const int rw = t >> 2;
  const int rpart = ((t & 3) ^ ((t >> 3) & 3)) * 8;
  int rB0 = m0 + rw;        if (rB0 > 11551) rB0 = 11551;
  int rB1 = m0 + 64 + rw;   if (rB1 > 11551) rB1 = 11551;
  const u16* pB0 = Bg + (size_t)rB0 * 1024 + rpart;
  const u16* pB1 = Bg + (size_t)rB1 * 1024 + rpart;

  u16* waS0 = &Wa[w * 512];
  u16* waS1 = &Wa[2048 + w * 512];
  u16* ibS0 = &Ib[w * 512];
  u16* ibS1 = &Ib[2048 + w * 512];

  const int aBase = (w >> 1) * 2048 + lane * 8;
  const int bBase = (w & 1) * 2048 + (lane & 15) * 32 +
                    (((lane >> 4) ^ ((lane >> 1) & 3))) * 8;

  f32x4 acc[4][4] = {};

  for (int kt = 0; kt < 32; ++kt) {
    const size_t off = (size_t)kt * 32;
    async16(pA0 + (size_t)kt * 4096, waS0);
    async16(pA0 + (size_t)kt * 4096 + 2048, waS1);
    async16(pB0 + off, ibS0);
    async16(pB1 + off, ibS1);
    __syncthreads();
    bf16x8 af[4], bfv[4];
#pragma unroll
    for (int i = 0; i < 4; ++i)
      af[i] = *(const bf16x8*)&Wa[aBase + i * 512];
#pragma unroll
    for (int j = 0; j < 4; ++j)
      bfv[j] = *(const bf16x8*)&Ib[bBase + j * 512];
#pragma unroll
    for (int i = 0; i < 4; ++i)
#pragma unroll
      for (int j = 0; j < 4; ++j)
        acc[i][j] = __builtin_amdgcn_mfma_f32_16x16x32_bf16(
            af[i], bfv[j], acc[i][j], 0, 0, 0);
    __syncthreads();
  }

  const int aRow = (w >> 1) * 64, bRow = (w & 1) * 64;
  const int lq = lane >> 4, lr = lane & 15;
#pragma unroll
  for (int j = 0; j < 4; ++j) {
    int m = m0 + bRow + j * 16 + lr;
    if (m >= 11552) continue;
    int b = m / 361, ij = m - b * 361;
    float* obase = out + (size_t)b * 216600 + ij;
#pragma unroll
    for (int i = 0; i < 4; ++i) {
      int cml = aRow + i * 16 + lq * 4;
#pragma unroll
      for (int r = 0; r < 4; ++r) {
        int cm = cm0 + cml + r;
        if (cm < 600) obase[(size_t)cm * 361] = acc[i][j][r] + sbias[cml + r];
      }
    }
  }
}

// ---------------------------------------------------------------------------
// launch: 3 nodes (was 7)
// ---------------------------------------------------------------------------
extern "C" void kernel_launch(void* const* d_in, const int* in_sizes, int n_in,
                              void* d_out, int out_size, void* d_ws, size_t ws_size,
                              hipStream_t stream)
{
  const float* stage6 = (const float*)d_in[0];
  const float* stage5 = (const float*)d_in[1];
  const float* w1 = (const float*)d_in[2];
  const float* g1 = (const float*)d_in[3];
  const float* b1 = (const float*)d_in[4];
  const float* m1 = (const float*)d_in[5];
  const float* v1 = (const float*)d_in[6];
  const float* w2 = (const float*)d_in[7];
  const float* g2 = (const float*)d_in[8];
  const float* b2 = (const float*)d_in[9];
  const float* m2 = (const float*)d_in[10];
  const float* v2 = (const float*)d_in[11];
  const float* meta = (const float*)d_in[12];
  float* out = (float*)d_out;

  char* ws = (char*)d_ws;
  u16*   in_bf  = (u16*)(ws);                  // 36,126,720 B  (32*21*21*1280 bf16)
  u16*   w2p    = (u16*)(ws + 36126720);       // 23,592,960 B  packed W
  u16*   prebf  = (u16*)(ws + 59719680);       // 23,658,496 B  (11552*1024 bf16)
  u16*   clsp   = (u16*)(ws + 83378176);       //  1,310,720 B  packed cls_w
  float* clsb   = (float*)(ws + 84688896);     //      2,560 B
  float* shift2 = (float*)(ws + 84691456);     //      4,096 B   total ~84.7 MB

  mega_prep_kern<<<18034, 256, 0, stream>>>(
      stage5, stage6, w1, g1, b1, m1, v1, w2, g2, b2, m2, v2, meta,
      in_bf, w2p, clsp, clsb, shift2);
  conv2_gemm_kern<<<dim3(91, 8), 256, 0, stream>>>(w2p, in_bf, shift2, prebf);
  einsum_gemm_kern<<<dim3(91, 5), 256, 0, stream>>>(clsp, prebf, clsb, out);
}